// Round 1
// baseline (444.754 us; speedup 1.0000x reference)
//
#include <hip/hip_runtime.h>
#include <stdint.h>

#define NND 50000
#define NED 640000
#define NCH 196   // ceil(NND/256)

typedef unsigned short u16;
typedef unsigned int u32;

__device__ __forceinline__ float bf2f(u16 u) {
    union { u32 i; float f; } x; x.i = ((u32)u) << 16; return x.f;
}
__device__ __forceinline__ u16 f2bf(float f) {
    union { u32 i; float f; } x; x.f = f;
    u32 u = x.i;
    return (u16)((u + 0x7fffu + ((u >> 16) & 1u)) >> 16);
}

// ============ CSR build ============
__global__ void k_count(const int* __restrict__ edst, int* __restrict__ deg) {
    int e = blockIdx.x * 256 + threadIdx.x;
    if (e < NED) atomicAdd(&deg[edst[e]], 1);
}

__global__ void k_bsum(const int* __restrict__ deg, int* __restrict__ bsums) {
    int i = blockIdx.x * 256 + threadIdx.x;
    int v = (i < NND) ? deg[i] : 0;
    #pragma unroll
    for (int m = 1; m < 64; m <<= 1) v += __shfl_xor(v, m, 64);
    __shared__ int ls[4];
    if ((threadIdx.x & 63) == 0) ls[threadIdx.x >> 6] = v;
    __syncthreads();
    if (threadIdx.x == 0) bsums[blockIdx.x] = ls[0] + ls[1] + ls[2] + ls[3];
}

__global__ void k_scan(int* __restrict__ bsums) {
    __shared__ int a[256];
    int t = threadIdx.x;
    int v = (t < NCH) ? bsums[t] : 0;
    a[t] = v;
    __syncthreads();
    for (int off = 1; off < 256; off <<= 1) {
        int add = (t >= off) ? a[t - off] : 0;
        __syncthreads();
        a[t] += add;
        __syncthreads();
    }
    if (t < NCH) bsums[t] = a[t] - v;   // exclusive block bases
}

__global__ void k_offsets(const int* __restrict__ deg, const int* __restrict__ bsums,
                          int* __restrict__ offs, int* __restrict__ cursor) {
    __shared__ int a[256];
    int t = threadIdx.x;
    int i = blockIdx.x * 256 + t;
    int v = (i < NND) ? deg[i] : 0;
    a[t] = v;
    __syncthreads();
    for (int off = 1; off < 256; off <<= 1) {
        int add = (t >= off) ? a[t - off] : 0;
        __syncthreads();
        a[t] += add;
        __syncthreads();
    }
    int excl = bsums[blockIdx.x] + a[t] - v;
    if (i < NND) {
        offs[i] = excl;
        cursor[i] = excl;
        if (i == NND - 1) offs[NND] = excl + v;
    }
}

__global__ void k_fill(const int* __restrict__ esrc, const int* __restrict__ edst,
                       int* __restrict__ cursor, int* __restrict__ csr) {
    int e = blockIdx.x * 256 + threadIdx.x;
    if (e < NED) {
        int pos = atomicAdd(&cursor[edst[e]], 1);
        csr[pos] = esrc[e];
    }
}

// ============ weight transpose (for coalesced GEMM loads) ============
__global__ void k_wt(const float* __restrict__ Wq, const float* __restrict__ Wk,
                     const float* __restrict__ Wv, const float* __restrict__ Ws,
                     const float* __restrict__ Wp,
                     float* __restrict__ wtq, float* __restrict__ wtk,
                     float* __restrict__ wtv, float* __restrict__ wts,
                     float* __restrict__ wpt) {
    int idx = blockIdx.x * 256 + threadIdx.x;
    if (idx < 4 * 16384) {
        int mat = idx >> 14;
        int w = idx & 16383;
        int r = w >> 6;     // out dim 0..255
        int c = w & 63;     // k 0..63
        const float* s = (mat == 0) ? Wq : (mat == 1) ? Wk : (mat == 2) ? Wv : Ws;
        float* d = (mat == 0) ? wtq : (mat == 1) ? wtk : (mat == 2) ? wtv : wts;
        d[c * 256 + r] = s[w];
    } else if (idx < 5 * 16384) {
        int w = idx - 4 * 16384;
        int o = w >> 8;     // 0..63
        int c = w & 255;    // 0..255
        wpt[c * 64 + o] = Wp[w];
    }
}

// ============ fused q/k/v/skip projections ============
// block: 256 threads (thread t = output dim), 16 nodes per block.
// q stored pre-scaled by 1/sqrt(64); q,k,v,x_r stored bf16.
__global__ __launch_bounds__(256) void k_proj(
    const float* __restrict__ x,
    const float* __restrict__ wtq, const float* __restrict__ wtk,
    const float* __restrict__ wtv, const float* __restrict__ wts,
    const float* __restrict__ bq, const float* __restrict__ bk,
    const float* __restrict__ bv, const float* __restrict__ bs,
    u16* __restrict__ qb, u16* __restrict__ kb,
    u16* __restrict__ vb, u16* __restrict__ xrb)
{
    const int t = threadIdx.x;
    const int nodeBase = blockIdx.x * 16;
    const float* xp = x + (size_t)nodeBase * 64;
    float aq[16], ak[16], av[16], ar[16];
    #pragma unroll
    for (int n = 0; n < 16; ++n) { aq[n] = 0.f; ak[n] = 0.f; av[n] = 0.f; ar[n] = 0.f; }
    for (int k = 0; k < 64; ++k) {
        float wq = wtq[k * 256 + t];
        float wk = wtk[k * 256 + t];
        float wv = wtv[k * 256 + t];
        float ws = wts[k * 256 + t];
        #pragma unroll
        for (int n = 0; n < 16; ++n) {
            float xv = xp[n * 64 + k];   // block-uniform -> scalar load
            aq[n] = fmaf(wq, xv, aq[n]);
            ak[n] = fmaf(wk, xv, ak[n]);
            av[n] = fmaf(wv, xv, av[n]);
            ar[n] = fmaf(ws, xv, ar[n]);
        }
    }
    float bqv = bq[t], bkv = bk[t], bvv = bv[t], bsv = bs[t];
    #pragma unroll
    for (int n = 0; n < 16; ++n) {
        size_t o = (size_t)(nodeBase + n) * 256 + t;
        qb[o]  = f2bf((aq[n] + bqv) * 0.125f);   // 1/sqrt(64) baked in
        kb[o]  = f2bf(ak[n] + bkv);
        vb[o]  = f2bf(av[n] + bvv);
        xrb[o] = f2bf(ar[n] + bsv);
    }
}

// ============ per-node attention with online softmax ============
// one wave per destination node; lane = head(4) x 16 lanes x 4 channels
__global__ __launch_bounds__(256) void k_attn(
    const int* __restrict__ offs, const int* __restrict__ csr,
    const u16* __restrict__ qb, const u16* __restrict__ kb,
    const u16* __restrict__ vb, u16* __restrict__ outb)
{
    const int wave = threadIdx.x >> 6;
    const int lane = threadIdx.x & 63;
    const int node = blockIdx.x * 4 + wave;
    if (node >= NND) return;
    const int d0 = (lane >> 4) * 64 + (lane & 15) * 4;
    ushort4 qu = *reinterpret_cast<const ushort4*>(qb + (size_t)node * 256 + d0);
    float q0 = bf2f(qu.x), q1 = bf2f(qu.y), q2 = bf2f(qu.z), q3 = bf2f(qu.w);
    int r0 = offs[node], r1 = offs[node + 1];
    float m = -1e30f, s = 0.f;
    float a0 = 0.f, a1 = 0.f, a2 = 0.f, a3 = 0.f;
    for (int i = r0; i < r1; ++i) {
        int src = csr[i];
        ushort4 ku = *reinterpret_cast<const ushort4*>(kb + (size_t)src * 256 + d0);
        ushort4 vu = *reinterpret_cast<const ushort4*>(vb + (size_t)src * 256 + d0);
        float p = q0 * bf2f(ku.x) + q1 * bf2f(ku.y) + q2 * bf2f(ku.z) + q3 * bf2f(ku.w);
        p += __shfl_xor(p, 1, 16);
        p += __shfl_xor(p, 2, 16);
        p += __shfl_xor(p, 4, 16);
        p += __shfl_xor(p, 8, 16);      // alpha, uniform within 16-lane head group
        float mn = fmaxf(m, p);
        float sc = __expf(m - mn);
        float pe = __expf(p - mn);
        s = s * sc + pe;
        float v0 = bf2f(vu.x), v1 = bf2f(vu.y), v2 = bf2f(vu.z), v3 = bf2f(vu.w);
        a0 = a0 * sc + pe * v0;
        a1 = a1 * sc + pe * v1;
        a2 = a2 * sc + pe * v2;
        a3 = a3 * sc + pe * v3;
        m = mn;
    }
    float inv = 1.0f / (s + 1e-16f);
    ushort4 ou;
    ou.x = f2bf(a0 * inv); ou.y = f2bf(a1 * inv);
    ou.z = f2bf(a2 * inv); ou.w = f2bf(a3 * inv);
    *reinterpret_cast<ushort4*>(outb + (size_t)node * 256 + d0) = ou;
}

// ============ epilogue: beta gate + LayerNorm + proj + residual ReLU ============
#define PS 260   // LDS row stride in u16 (pad breaks 4-way node-group conflicts)
__global__ __launch_bounds__(256) void k_epi(
    const u16* __restrict__ outb, const u16* __restrict__ xrb,
    const float* __restrict__ x, const float* __restrict__ Wbeta,
    const float* __restrict__ ln_g, const float* __restrict__ ln_b,
    const float* __restrict__ wpt, const float* __restrict__ bproj,
    float* __restrict__ y)
{
    __shared__ u16 hn[64 * PS];   // 33,280 B
    const int t = threadIdx.x;
    const int wave = t >> 6, lane = t & 63;
    const float4* wb4 = reinterpret_cast<const float4*>(Wbeta);
    const float4 wbo = wb4[lane], wbx = wb4[64 + lane], wbd = wb4[128 + lane];
    const float4 g4 = reinterpret_cast<const float4*>(ln_g)[lane];
    const float4 b4 = reinterpret_cast<const float4*>(ln_b)[lane];
    const int og = t & 15, ng = t >> 4;
    const float4 bp4 = reinterpret_cast<const float4*>(bproj)[og];
    const float4* wpt4 = reinterpret_cast<const float4*>(wpt);

    for (int blk = blockIdx.x; blk < (NND + 63) / 64; blk += gridDim.x) {
        const int base = blk * 64;
        // phase 1: wave-per-node beta gate + LN -> hn tile (bf16 LDS)
        for (int it = 0; it < 16; ++it) {
            int lid = wave * 16 + it;
            int node = base + lid;
            if (node < NND) {
                size_t ix = (size_t)node * 256 + lane * 4;
                ushort4 ou = *reinterpret_cast<const ushort4*>(outb + ix);
                ushort4 xu = *reinterpret_cast<const ushort4*>(xrb + ix);
                float o0 = bf2f(ou.x), o1 = bf2f(ou.y), o2 = bf2f(ou.z), o3 = bf2f(ou.w);
                float r0 = bf2f(xu.x), r1 = bf2f(xu.y), r2 = bf2f(xu.z), r3 = bf2f(xu.w);
                float part = wbo.x*o0 + wbo.y*o1 + wbo.z*o2 + wbo.w*o3
                           + wbx.x*r0 + wbx.y*r1 + wbx.z*r2 + wbx.w*r3
                           + wbd.x*(o0-r0) + wbd.y*(o1-r1) + wbd.z*(o2-r2) + wbd.w*(o3-r3);
                #pragma unroll
                for (int mm = 1; mm < 64; mm <<= 1) part += __shfl_xor(part, mm, 64);
                float beta = 1.0f / (1.0f + __expf(-part));
                float h0 = beta * r0 + (1.f - beta) * o0;
                float h1 = beta * r1 + (1.f - beta) * o1;
                float h2 = beta * r2 + (1.f - beta) * o2;
                float h3 = beta * r3 + (1.f - beta) * o3;
                float sh = h0 + h1 + h2 + h3;
                float sq = h0*h0 + h1*h1 + h2*h2 + h3*h3;
                #pragma unroll
                for (int mm = 1; mm < 64; mm <<= 1) {
                    sh += __shfl_xor(sh, mm, 64);
                    sq += __shfl_xor(sq, mm, 64);
                }
                float mu = sh * (1.0f / 256.0f);
                float var = sq * (1.0f / 256.0f) - mu * mu;
                float ri = rsqrtf(var + 1e-5f);
                ushort4 hv;
                hv.x = f2bf((h0 - mu) * ri * g4.x + b4.x);
                hv.y = f2bf((h1 - mu) * ri * g4.y + b4.y);
                hv.z = f2bf((h2 - mu) * ri * g4.z + b4.z);
                hv.w = f2bf((h3 - mu) * ri * g4.w + b4.w);
                *reinterpret_cast<ushort4*>(&hn[lid * PS + lane * 4]) = hv;
            }
        }
        __syncthreads();
        // phase 2: register-tiled GEMM  y = relu(hn @ Wp^T + bproj + x)
        // thread: og = 4 output dims, ng = 4 nodes
        float acc[4][4];
        #pragma unroll
        for (int a = 0; a < 4; ++a)
            #pragma unroll
            for (int b = 0; b < 4; ++b) acc[a][b] = 0.f;
        for (int c4 = 0; c4 < 64; ++c4) {
            int c = c4 * 4;
            float4 w0 = wpt4[(c + 0) * 16 + og];
            float4 w1 = wpt4[(c + 1) * 16 + og];
            float4 w2 = wpt4[(c + 2) * 16 + og];
            float4 w3 = wpt4[(c + 3) * 16 + og];
            #pragma unroll
            for (int nn = 0; nn < 4; ++nn) {
                ushort4 hu = *reinterpret_cast<const ushort4*>(&hn[(ng * 4 + nn) * PS + c]);
                float h0 = bf2f(hu.x), h1 = bf2f(hu.y), h2 = bf2f(hu.z), h3 = bf2f(hu.w);
                acc[nn][0] = fmaf(h0, w0.x, acc[nn][0]);
                acc[nn][1] = fmaf(h0, w0.y, acc[nn][1]);
                acc[nn][2] = fmaf(h0, w0.z, acc[nn][2]);
                acc[nn][3] = fmaf(h0, w0.w, acc[nn][3]);
                acc[nn][0] = fmaf(h1, w1.x, acc[nn][0]);
                acc[nn][1] = fmaf(h1, w1.y, acc[nn][1]);
                acc[nn][2] = fmaf(h1, w1.z, acc[nn][2]);
                acc[nn][3] = fmaf(h1, w1.w, acc[nn][3]);
                acc[nn][0] = fmaf(h2, w2.x, acc[nn][0]);
                acc[nn][1] = fmaf(h2, w2.y, acc[nn][1]);
                acc[nn][2] = fmaf(h2, w2.z, acc[nn][2]);
                acc[nn][3] = fmaf(h2, w2.w, acc[nn][3]);
                acc[nn][0] = fmaf(h3, w3.x, acc[nn][0]);
                acc[nn][1] = fmaf(h3, w3.y, acc[nn][1]);
                acc[nn][2] = fmaf(h3, w3.z, acc[nn][2]);
                acc[nn][3] = fmaf(h3, w3.w, acc[nn][3]);
            }
        }
        #pragma unroll
        for (int nn = 0; nn < 4; ++nn) {
            int node = base + ng * 4 + nn;
            if (node < NND) {
                float4 xv = reinterpret_cast<const float4*>(x)[node * 16 + og];
                float4 r;
                r.x = fmaxf(acc[nn][0] + bp4.x + xv.x, 0.f);
                r.y = fmaxf(acc[nn][1] + bp4.y + xv.y, 0.f);
                r.z = fmaxf(acc[nn][2] + bp4.z + xv.z, 0.f);
                r.w = fmaxf(acc[nn][3] + bp4.w + xv.w, 0.f);
                reinterpret_cast<float4*>(y)[node * 16 + og] = r;
            }
        }
        __syncthreads();
    }
}

extern "C" void kernel_launch(void* const* d_in, const int* in_sizes, int n_in,
                              void* d_out, int out_size, void* d_ws, size_t ws_size,
                              hipStream_t stream) {
    const float* x     = (const float*)d_in[0];
    const int*   eidx  = (const int*)d_in[1];
    const float* Wq    = (const float*)d_in[2];
    const float* bq    = (const float*)d_in[3];
    const float* Wk    = (const float*)d_in[4];
    const float* bk    = (const float*)d_in[5];
    const float* Wv    = (const float*)d_in[6];
    const float* bv    = (const float*)d_in[7];
    const float* Wsk   = (const float*)d_in[8];
    const float* bsk   = (const float*)d_in[9];
    const float* Wbeta = (const float*)d_in[10];
    const float* lng   = (const float*)d_in[11];
    const float* lnb   = (const float*)d_in[12];
    const float* Wp    = (const float*)d_in[13];
    const float* bp    = (const float*)d_in[14];
    float* y = (float*)d_out;

    char* ws = (char*)d_ws;
    size_t off = 0;
    auto alloc = [&](size_t b) { size_t o = off; off += (b + 255) & ~(size_t)255; return o; };
    u16* qb   = (u16*)(ws + alloc((size_t)NND * 256 * 2));
    u16* kb   = (u16*)(ws + alloc((size_t)NND * 256 * 2));
    u16* vb   = (u16*)(ws + alloc((size_t)NND * 256 * 2));
    u16* xrb  = (u16*)(ws + alloc((size_t)NND * 256 * 2));
    u16* outb = (u16*)(ws + alloc((size_t)NND * 256 * 2));
    int* deg    = (int*)(ws + alloc((size_t)NND * 4));
    int* offs   = (int*)(ws + alloc((size_t)(NND + 1) * 4));
    int* cursor = (int*)(ws + alloc((size_t)NND * 4));
    int* csr    = (int*)(ws + alloc((size_t)NED * 4));
    int* bsums  = (int*)(ws + alloc((size_t)NCH * 4));
    float* wtq = (float*)(ws + alloc((size_t)16384 * 4));
    float* wtk = (float*)(ws + alloc((size_t)16384 * 4));
    float* wtv = (float*)(ws + alloc((size_t)16384 * 4));
    float* wts = (float*)(ws + alloc((size_t)16384 * 4));
    float* wpt = (float*)(ws + alloc((size_t)16384 * 4));

    hipMemsetAsync(deg, 0, (size_t)NND * 4, stream);
    k_count  <<<(NED + 255) / 256, 256, 0, stream>>>(eidx + NED, deg);
    k_bsum   <<<NCH, 256, 0, stream>>>(deg, bsums);
    k_scan   <<<1, 256, 0, stream>>>(bsums);
    k_offsets<<<NCH, 256, 0, stream>>>(deg, bsums, offs, cursor);
    k_fill   <<<(NED + 255) / 256, 256, 0, stream>>>(eidx, eidx + NED, cursor, csr);
    k_wt     <<<(5 * 16384 + 255) / 256, 256, 0, stream>>>(Wq, Wk, Wv, Wsk, Wp,
                                                           wtq, wtk, wtv, wts, wpt);
    k_proj   <<<NND / 16, 256, 0, stream>>>(x, wtq, wtk, wtv, wts,
                                            bq, bk, bv, bsk, qb, kb, vb, xrb);
    k_attn   <<<(NND + 3) / 4, 256, 0, stream>>>(offs, csr, qb, kb, vb, outb);
    k_epi    <<<512, 256, 0, stream>>>(outb, xrb, x, Wbeta, lng, lnb, wpt, bp, y);
}

// Round 2
// 360.973 us; speedup vs baseline: 1.2321x; 1.2321x over previous
//
#include <hip/hip_runtime.h>
#include <stdint.h>

#define NND 50000
#define NED 640000
#define NCH 196   // ceil(NND/256)

typedef unsigned short u16;
typedef unsigned int u32;
typedef __attribute__((ext_vector_type(8))) short short8;
typedef __attribute__((ext_vector_type(4))) float f32x4;

__device__ __forceinline__ float bf2f(u16 u) {
    union { u32 i; float f; } x; x.i = ((u32)u) << 16; return x.f;
}
__device__ __forceinline__ u16 f2bf(float f) {
    union { u32 i; float f; } x; x.f = f;
    u32 u = x.i;
    return (u16)((u + 0x7fffu + ((u >> 16) & 1u)) >> 16);
}
__device__ __forceinline__ float bflo(u32 w) {
    union { u32 i; float f; } x; x.i = w << 16; return x.f;
}
__device__ __forceinline__ float bfhi(u32 w) {
    union { u32 i; float f; } x; x.i = w & 0xffff0000u; return x.f;
}
__device__ __forceinline__ u32 pk2(float lo, float hi) {
    return (u32)f2bf(lo) | ((u32)f2bf(hi) << 16);
}

// ============ CSR build ============
__global__ void k_count(const int* __restrict__ edst, int* __restrict__ deg) {
    int e = blockIdx.x * 256 + threadIdx.x;
    if (e < NED) atomicAdd(&deg[edst[e]], 1);
}

__global__ void k_bsum(const int* __restrict__ deg, int* __restrict__ bsums) {
    int i = blockIdx.x * 256 + threadIdx.x;
    int v = (i < NND) ? deg[i] : 0;
    #pragma unroll
    for (int m = 1; m < 64; m <<= 1) v += __shfl_xor(v, m, 64);
    __shared__ int ls[4];
    if ((threadIdx.x & 63) == 0) ls[threadIdx.x >> 6] = v;
    __syncthreads();
    if (threadIdx.x == 0) bsums[blockIdx.x] = ls[0] + ls[1] + ls[2] + ls[3];
}

__global__ void k_scan(int* __restrict__ bsums) {
    __shared__ int a[256];
    int t = threadIdx.x;
    int v = (t < NCH) ? bsums[t] : 0;
    a[t] = v;
    __syncthreads();
    for (int off = 1; off < 256; off <<= 1) {
        int add = (t >= off) ? a[t - off] : 0;
        __syncthreads();
        a[t] += add;
        __syncthreads();
    }
    if (t < NCH) bsums[t] = a[t] - v;
}

__global__ void k_offsets(const int* __restrict__ deg, const int* __restrict__ bsums,
                          int* __restrict__ offs, int* __restrict__ cursor) {
    __shared__ int a[256];
    int t = threadIdx.x;
    int i = blockIdx.x * 256 + t;
    int v = (i < NND) ? deg[i] : 0;
    a[t] = v;
    __syncthreads();
    for (int off = 1; off < 256; off <<= 1) {
        int add = (t >= off) ? a[t - off] : 0;
        __syncthreads();
        a[t] += add;
        __syncthreads();
    }
    int excl = bsums[blockIdx.x] + a[t] - v;
    if (i < NND) {
        offs[i] = excl;
        cursor[i] = excl;
        if (i == NND - 1) offs[NND] = excl + v;
    }
}

__global__ void k_fill(const int* __restrict__ esrc, const int* __restrict__ edst,
                       int* __restrict__ cursor, int* __restrict__ csr) {
    int e = blockIdx.x * 256 + threadIdx.x;
    if (e < NED) {
        int pos = atomicAdd(&cursor[edst[e]], 1);
        csr[pos] = esrc[e];
    }
}

// ============ weight prep ============
// wb: A-operand-fragment-ordered bf16 combined weights [1024 dims x 64 k]
//   wb[((dt*2+q)*64 + lane)*8 + j] = W[dim=dt*16+(lane&15)][k=q*32+((lane>>4)&3)*8+j]
// bias_c: combined bias [1024] fp32.  q-part (dims 0..255) scaled by 0.125.
// wpt: proj weight transposed fp32 [256][64].
__global__ void k_wt(const float* __restrict__ Wq, const float* __restrict__ Wk,
                     const float* __restrict__ Wv, const float* __restrict__ Ws,
                     const float* __restrict__ Wp,
                     const float* __restrict__ bq, const float* __restrict__ bk,
                     const float* __restrict__ bv, const float* __restrict__ bs,
                     u16* __restrict__ wb, float* __restrict__ bias_c,
                     float* __restrict__ wpt) {
    int idx = blockIdx.x * 256 + threadIdx.x;
    if (idx < 65536) {
        int j = idx & 7;
        int lane = (idx >> 3) & 63;
        int q = (idx >> 9) & 1;
        int dt = idx >> 10;
        int dim = dt * 16 + (lane & 15);
        int k = q * 32 + ((lane >> 4) & 3) * 8 + j;
        int mat = dim >> 8, r = dim & 255;
        const float* W = (mat == 0) ? Wq : (mat == 1) ? Wk : (mat == 2) ? Wv : Ws;
        float v = W[r * 64 + k] * ((mat == 0) ? 0.125f : 1.0f);
        wb[idx] = f2bf(v);
    } else if (idx < 65536 + 1024) {
        int dim = idx - 65536;
        int mat = dim >> 8, r = dim & 255;
        const float* B = (mat == 0) ? bq : (mat == 1) ? bk : (mat == 2) ? bv : bs;
        bias_c[dim] = B[r] * ((mat == 0) ? 0.125f : 1.0f);
    } else if (idx < 65536 + 1024 + 16384) {
        int w = idx - 66560;
        int o = w >> 8, c = w & 255;
        wpt[c * 64 + o] = Wp[w];
    }
}

// ============ fused q/k/v/skip projections via MFMA ============
// 64 nodes/block, 4 waves; wave w computes dims [w*256, w*256+256).
// Output qkvs[node][1024] bf16: [q(0-255) | k(256-511) | v(512-767) | xr(768-1023)]
__global__ __launch_bounds__(256) void k_proj(
    const float* __restrict__ x, const u16* __restrict__ wb,
    const float* __restrict__ bias_c, u16* __restrict__ qkvs)
{
    const int wave = threadIdx.x >> 6, lane = threadIdx.x & 63;
    const int nbase = blockIdx.x * 64;
    const int lr = lane & 15, quad = lane >> 4;

    // B-operand x fragments: 4 node-tiles x 2 k-halves; lane holds x[n=lr][k=quad*8+j]
    short8 xf[4][2];
    #pragma unroll
    for (int nt = 0; nt < 4; ++nt) {
        int node = nbase + nt * 16 + lr;
        if (node > NND - 1) node = NND - 1;
        #pragma unroll
        for (int kh = 0; kh < 2; ++kh) {
            const float* xp = x + (size_t)node * 64 + kh * 32 + quad * 8;
            float4 a = *reinterpret_cast<const float4*>(xp);
            float4 b = *reinterpret_cast<const float4*>(xp + 4);
            short8 f;
            f[0] = (short)f2bf(a.x); f[1] = (short)f2bf(a.y);
            f[2] = (short)f2bf(a.z); f[3] = (short)f2bf(a.w);
            f[4] = (short)f2bf(b.x); f[5] = (short)f2bf(b.y);
            f[6] = (short)f2bf(b.z); f[7] = (short)f2bf(b.w);
            xf[nt][kh] = f;
        }
    }

    for (int dtl = 0; dtl < 16; ++dtl) {
        int dt = wave * 16 + dtl;
        const u16* wp = wb + (size_t)(dt * 2) * 512 + lane * 8;
        short8 a0 = *reinterpret_cast<const short8*>(wp);
        short8 a1 = *reinterpret_cast<const short8*>(wp + 512);
        f32x4 bias = *reinterpret_cast<const f32x4*>(bias_c + dt * 16 + quad * 4);
        #pragma unroll
        for (int nt = 0; nt < 4; ++nt) {
            f32x4 acc = {0.f, 0.f, 0.f, 0.f};
            acc = __builtin_amdgcn_mfma_f32_16x16x32_bf16(a0, xf[nt][0], acc, 0, 0, 0);
            acc = __builtin_amdgcn_mfma_f32_16x16x32_bf16(a1, xf[nt][1], acc, 0, 0, 0);
            int node = nbase + nt * 16 + lr;
            if (node < NND) {
                // C layout: col(n)=lane&15 -> node, row(m)=quad*4+reg -> dim
                u32 lo = pk2(acc[0] + bias[0], acc[1] + bias[1]);
                u32 hi = pk2(acc[2] + bias[2], acc[3] + bias[3]);
                uint2 st; st.x = lo; st.y = hi;
                *reinterpret_cast<uint2*>(qkvs + (size_t)node * 1024 + dt * 16 + quad * 4) = st;
            }
        }
    }
}

// ============ per-node attention, online softmax, 2 edges/wave-step x2 ============
// lane = half(2) x 32 lanes x 8 channels; head = ((lane&31)>>3)
__global__ __launch_bounds__(256) void k_attn(
    const int* __restrict__ offs, const int* __restrict__ csr,
    u16* __restrict__ qkvs)
{
    const int wave = threadIdx.x >> 6;
    const int lane = threadIdx.x & 63;
    const int node = blockIdx.x * 4 + wave;
    if (node >= NND) return;
    const int l32 = lane & 31;
    const int half = lane >> 5;
    const int ch0 = l32 * 8;
    u16* nrow = qkvs + (size_t)node * 1024;

    uint4 qv = *reinterpret_cast<const uint4*>(nrow + ch0);
    float q0 = bflo(qv.x), q1 = bfhi(qv.x), q2 = bflo(qv.y), q3 = bfhi(qv.y);
    float q4 = bflo(qv.z), q5 = bfhi(qv.z), q6 = bflo(qv.w), q7 = bfhi(qv.w);

    int r0 = __builtin_amdgcn_readfirstlane(offs[node]);
    int r1 = __builtin_amdgcn_readfirstlane(offs[node + 1]);

    float m = -1e30f, s = 0.f;
    float a0 = 0.f, a1 = 0.f, a2 = 0.f, a3 = 0.f;
    float a4 = 0.f, a5 = 0.f, a6 = 0.f, a7 = 0.f;

    int i = r0;
    for (; i + 4 <= r1; i += 4) {
        int s0 = csr[i], s1 = csr[i + 1], s2 = csr[i + 2], s3 = csr[i + 3];
        int sA = half ? s1 : s0;
        int sB = half ? s3 : s2;
        const u16* pA = qkvs + (size_t)sA * 1024;
        const u16* pB = qkvs + (size_t)sB * 1024;
        uint4 kA = *reinterpret_cast<const uint4*>(pA + 256 + ch0);
        uint4 vA = *reinterpret_cast<const uint4*>(pA + 512 + ch0);
        uint4 kB = *reinterpret_cast<const uint4*>(pB + 256 + ch0);
        uint4 vB = *reinterpret_cast<const uint4*>(pB + 512 + ch0);

        float pa = q0 * bflo(kA.x) + q1 * bfhi(kA.x) + q2 * bflo(kA.y) + q3 * bfhi(kA.y)
                 + q4 * bflo(kA.z) + q5 * bfhi(kA.z) + q6 * bflo(kA.w) + q7 * bfhi(kA.w);
        float pb = q0 * bflo(kB.x) + q1 * bfhi(kB.x) + q2 * bflo(kB.y) + q3 * bfhi(kB.y)
                 + q4 * bflo(kB.z) + q5 * bfhi(kB.z) + q6 * bflo(kB.w) + q7 * bfhi(kB.w);
        pa += __shfl_xor(pa, 1); pa += __shfl_xor(pa, 2); pa += __shfl_xor(pa, 4);
        pb += __shfl_xor(pb, 1); pb += __shfl_xor(pb, 2); pb += __shfl_xor(pb, 4);
        float poa = __shfl_xor(pa, 32);
        float pob = __shfl_xor(pb, 32);

        float mb = fmaxf(m, fmaxf(fmaxf(pa, poa), fmaxf(pb, pob)));
        float sc = __expf(m - mb);
        float ea = __expf(pa - mb), eoa = __expf(poa - mb);
        float eb = __expf(pb - mb), eob = __expf(pob - mb);
        s = s * sc + ea + eoa + eb + eob;
        a0 = fmaf(eb, bflo(vB.x), fmaf(ea, bflo(vA.x), a0 * sc));
        a1 = fmaf(eb, bfhi(vB.x), fmaf(ea, bfhi(vA.x), a1 * sc));
        a2 = fmaf(eb, bflo(vB.y), fmaf(ea, bflo(vA.y), a2 * sc));
        a3 = fmaf(eb, bfhi(vB.y), fmaf(ea, bfhi(vA.y), a3 * sc));
        a4 = fmaf(eb, bflo(vB.z), fmaf(ea, bflo(vA.z), a4 * sc));
        a5 = fmaf(eb, bfhi(vB.z), fmaf(ea, bfhi(vA.z), a5 * sc));
        a6 = fmaf(eb, bflo(vB.w), fmaf(ea, bflo(vA.w), a6 * sc));
        a7 = fmaf(eb, bfhi(vB.w), fmaf(ea, bfhi(vA.w), a7 * sc));
        m = mb;
    }
    for (; i < r1; i += 2) {
        int s0 = csr[i];
        int s1 = (i + 1 < r1) ? csr[i + 1] : s0;
        int sA = half ? s1 : s0;
        const u16* pA = qkvs + (size_t)sA * 1024;
        uint4 kA = *reinterpret_cast<const uint4*>(pA + 256 + ch0);
        uint4 vA = *reinterpret_cast<const uint4*>(pA + 512 + ch0);
        float pa = q0 * bflo(kA.x) + q1 * bfhi(kA.x) + q2 * bflo(kA.y) + q3 * bfhi(kA.y)
                 + q4 * bflo(kA.z) + q5 * bfhi(kA.z) + q6 * bflo(kA.w) + q7 * bfhi(kA.w);
        pa += __shfl_xor(pa, 1); pa += __shfl_xor(pa, 2); pa += __shfl_xor(pa, 4);
        if (half && (i + 1 >= r1)) pa = -1e30f;   // dummy edge in half B
        float poa = __shfl_xor(pa, 32);
        float mb = fmaxf(m, fmaxf(pa, poa));
        float sc = __expf(m - mb);
        float ea = __expf(pa - mb), eoa = __expf(poa - mb);
        s = s * sc + ea + eoa;
        a0 = fmaf(ea, bflo(vA.x), a0 * sc);
        a1 = fmaf(ea, bfhi(vA.x), a1 * sc);
        a2 = fmaf(ea, bflo(vA.y), a2 * sc);
        a3 = fmaf(ea, bfhi(vA.y), a3 * sc);
        a4 = fmaf(ea, bflo(vA.z), a4 * sc);
        a5 = fmaf(ea, bfhi(vA.z), a5 * sc);
        a6 = fmaf(ea, bflo(vA.w), a6 * sc);
        a7 = fmaf(ea, bfhi(vA.w), a7 * sc);
        m = mb;
    }
    // combine halves, normalize, store into (dead) q-section as `out`
    a0 += __shfl_xor(a0, 32); a1 += __shfl_xor(a1, 32);
    a2 += __shfl_xor(a2, 32); a3 += __shfl_xor(a3, 32);
    a4 += __shfl_xor(a4, 32); a5 += __shfl_xor(a5, 32);
    a6 += __shfl_xor(a6, 32); a7 += __shfl_xor(a7, 32);
    float inv = 1.0f / (s + 1e-16f);
    if (half == 0) {
        uint4 st;
        st.x = pk2(a0 * inv, a1 * inv);
        st.y = pk2(a2 * inv, a3 * inv);
        st.z = pk2(a4 * inv, a5 * inv);
        st.w = pk2(a6 * inv, a7 * inv);
        *reinterpret_cast<uint4*>(nrow + ch0) = st;
    }
}

// ============ epilogue: beta gate + LayerNorm + proj + residual ReLU ============
#define PS 260   // LDS row stride in u16
__global__ __launch_bounds__(256) void k_epi(
    const u16* __restrict__ qkvs, const float* __restrict__ x,
    const float* __restrict__ Wbeta, const float* __restrict__ ln_g,
    const float* __restrict__ ln_b, const float* __restrict__ wpt,
    const float* __restrict__ bproj, float* __restrict__ y)
{
    __shared__ u16 hn[64 * PS];
    const int t = threadIdx.x;
    const int wave = t >> 6, lane = t & 63;
    const float4* wb4 = reinterpret_cast<const float4*>(Wbeta);
    const float4 wbo = wb4[lane], wbx = wb4[64 + lane], wbd = wb4[128 + lane];
    const float4 g4 = reinterpret_cast<const float4*>(ln_g)[lane];
    const float4 b4 = reinterpret_cast<const float4*>(ln_b)[lane];
    const int og = t & 15, ng = t >> 4;
    const float4 bp4 = reinterpret_cast<const float4*>(bproj)[og];
    const float4* wpt4 = reinterpret_cast<const float4*>(wpt);

    const int base = blockIdx.x * 64;
    // phase 1: wave-per-node beta gate + LN -> hn tile (bf16 LDS)
    for (int it = 0; it < 16; ++it) {
        int lid = wave * 16 + it;
        int node = base + lid;
        if (node < NND) {
            const u16* nrow = qkvs + (size_t)node * 1024;
            ushort4 ou = *reinterpret_cast<const ushort4*>(nrow + lane * 4);        // out
            ushort4 xu = *reinterpret_cast<const ushort4*>(nrow + 768 + lane * 4);  // x_r
            float o0 = bf2f(ou.x), o1 = bf2f(ou.y), o2 = bf2f(ou.z), o3 = bf2f(ou.w);
            float r0 = bf2f(xu.x), r1 = bf2f(xu.y), r2 = bf2f(xu.z), r3 = bf2f(xu.w);
            float part = wbo.x*o0 + wbo.y*o1 + wbo.z*o2 + wbo.w*o3
                       + wbx.x*r0 + wbx.y*r1 + wbx.z*r2 + wbx.w*r3
                       + wbd.x*(o0-r0) + wbd.y*(o1-r1) + wbd.z*(o2-r2) + wbd.w*(o3-r3);
            #pragma unroll
            for (int mm = 1; mm < 64; mm <<= 1) part += __shfl_xor(part, mm, 64);
            float beta = 1.0f / (1.0f + __expf(-part));
            float h0 = beta * r0 + (1.f - beta) * o0;
            float h1 = beta * r1 + (1.f - beta) * o1;
            float h2 = beta * r2 + (1.f - beta) * o2;
            float h3 = beta * r3 + (1.f - beta) * o3;
            float sh = h0 + h1 + h2 + h3;
            float sq = h0*h0 + h1*h1 + h2*h2 + h3*h3;
            #pragma unroll
            for (int mm = 1; mm < 64; mm <<= 1) {
                sh += __shfl_xor(sh, mm, 64);
                sq += __shfl_xor(sq, mm, 64);
            }
            float mu = sh * (1.0f / 256.0f);
            float var = sq * (1.0f / 256.0f) - mu * mu;
            float ri = rsqrtf(var + 1e-5f);
            ushort4 hv;
            hv.x = f2bf((h0 - mu) * ri * g4.x + b4.x);
            hv.y = f2bf((h1 - mu) * ri * g4.y + b4.y);
            hv.z = f2bf((h2 - mu) * ri * g4.z + b4.z);
            hv.w = f2bf((h3 - mu) * ri * g4.w + b4.w);
            *reinterpret_cast<ushort4*>(&hn[lid * PS + lane * 4]) = hv;
        }
    }
    __syncthreads();
    // phase 2: register-tiled GEMM  y = relu(hn @ Wp^T + bproj + x)
    float acc[4][4];
    #pragma unroll
    for (int a = 0; a < 4; ++a)
        #pragma unroll
        for (int b = 0; b < 4; ++b) acc[a][b] = 0.f;
    for (int c4 = 0; c4 < 64; ++c4) {
        int c = c4 * 4;
        float4 w0 = wpt4[(c + 0) * 16 + og];
        float4 w1 = wpt4[(c + 1) * 16 + og];
        float4 w2 = wpt4[(c + 2) * 16 + og];
        float4 w3 = wpt4[(c + 3) * 16 + og];
        #pragma unroll
        for (int nn = 0; nn < 4; ++nn) {
            ushort4 hu = *reinterpret_cast<const ushort4*>(&hn[(ng * 4 + nn) * PS + c]);
            float h0 = bf2f(hu.x), h1 = bf2f(hu.y), h2 = bf2f(hu.z), h3 = bf2f(hu.w);
            acc[nn][0] = fmaf(h0, w0.x, acc[nn][0]);
            acc[nn][1] = fmaf(h0, w0.y, acc[nn][1]);
            acc[nn][2] = fmaf(h0, w0.z, acc[nn][2]);
            acc[nn][3] = fmaf(h0, w0.w, acc[nn][3]);
            acc[nn][0] = fmaf(h1, w1.x, acc[nn][0]);
            acc[nn][1] = fmaf(h1, w1.y, acc[nn][1]);
            acc[nn][2] = fmaf(h1, w1.z, acc[nn][2]);
            acc[nn][3] = fmaf(h1, w1.w, acc[nn][3]);
            acc[nn][0] = fmaf(h2, w2.x, acc[nn][0]);
            acc[nn][1] = fmaf(h2, w2.y, acc[nn][1]);
            acc[nn][2] = fmaf(h2, w2.z, acc[nn][2]);
            acc[nn][3] = fmaf(h2, w2.w, acc[nn][3]);
            acc[nn][0] = fmaf(h3, w3.x, acc[nn][0]);
            acc[nn][1] = fmaf(h3, w3.y, acc[nn][1]);
            acc[nn][2] = fmaf(h3, w3.z, acc[nn][2]);
            acc[nn][3] = fmaf(h3, w3.w, acc[nn][3]);
        }
    }
    #pragma unroll
    for (int nn = 0; nn < 4; ++nn) {
        int node = base + ng * 4 + nn;
        if (node < NND) {
            float4 xv = reinterpret_cast<const float4*>(x)[node * 16 + og];
            float4 r;
            r.x = fmaxf(acc[nn][0] + bp4.x + xv.x, 0.f);
            r.y = fmaxf(acc[nn][1] + bp4.y + xv.y, 0.f);
            r.z = fmaxf(acc[nn][2] + bp4.z + xv.z, 0.f);
            r.w = fmaxf(acc[nn][3] + bp4.w + xv.w, 0.f);
            reinterpret_cast<float4*>(y)[node * 16 + og] = r;
        }
    }
}

extern "C" void kernel_launch(void* const* d_in, const int* in_sizes, int n_in,
                              void* d_out, int out_size, void* d_ws, size_t ws_size,
                              hipStream_t stream) {
    const float* x     = (const float*)d_in[0];
    const int*   eidx  = (const int*)d_in[1];
    const float* Wq    = (const float*)d_in[2];
    const float* bq    = (const float*)d_in[3];
    const float* Wk    = (const float*)d_in[4];
    const float* bk    = (const float*)d_in[5];
    const float* Wv    = (const float*)d_in[6];
    const float* bv    = (const float*)d_in[7];
    const float* Wsk   = (const float*)d_in[8];
    const float* bsk   = (const float*)d_in[9];
    const float* Wbeta = (const float*)d_in[10];
    const float* lng   = (const float*)d_in[11];
    const float* lnb   = (const float*)d_in[12];
    const float* Wp    = (const float*)d_in[13];
    const float* bp    = (const float*)d_in[14];
    float* y = (float*)d_out;

    char* ws = (char*)d_ws;
    size_t off = 0;
    auto alloc = [&](size_t b) { size_t o = off; off += (b + 255) & ~(size_t)255; return o; };
    u16* qkvs = (u16*)(ws + alloc((size_t)NND * 1024 * 2));
    int* deg    = (int*)(ws + alloc((size_t)NND * 4));
    int* offs   = (int*)(ws + alloc((size_t)(NND + 1) * 4));
    int* cursor = (int*)(ws + alloc((size_t)NND * 4));
    int* csr    = (int*)(ws + alloc((size_t)NED * 4));
    int* bsums  = (int*)(ws + alloc((size_t)NCH * 4));
    u16* wb     = (u16*)(ws + alloc((size_t)65536 * 2));
    float* bias_c = (float*)(ws + alloc((size_t)1024 * 4));
    float* wpt  = (float*)(ws + alloc((size_t)16384 * 4));

    hipMemsetAsync(deg, 0, (size_t)NND * 4, stream);
    k_count  <<<(NED + 255) / 256, 256, 0, stream>>>(eidx + NED, deg);
    k_bsum   <<<NCH, 256, 0, stream>>>(deg, bsums);
    k_scan   <<<1, 256, 0, stream>>>(bsums);
    k_offsets<<<NCH, 256, 0, stream>>>(deg, bsums, offs, cursor);
    k_fill   <<<(NED + 255) / 256, 256, 0, stream>>>(eidx, eidx + NED, cursor, csr);
    k_wt     <<<(66560 + 16384 + 255) / 256, 256, 0, stream>>>(
                 Wq, Wk, Wv, Wsk, Wp, bq, bk, bv, bsk, wb, bias_c, wpt);
    k_proj   <<<(NND + 63) / 64, 256, 0, stream>>>(x, wb, bias_c, qkvs);
    k_attn   <<<(NND + 3) / 4, 256, 0, stream>>>(offs, csr, qkvs);
    k_epi    <<<(NND + 63) / 64, 256, 0, stream>>>(qkvs, x, Wbeta, lng, lnb, wpt, bp, y);
}

// Round 3
// 343.677 us; speedup vs baseline: 1.2941x; 1.0503x over previous
//
#include <hip/hip_runtime.h>
#include <stdint.h>

#define NND 50000
#define NED 640000
#define NCH 196   // ceil(NND/256)

typedef unsigned short u16;
typedef unsigned int u32;
typedef __attribute__((ext_vector_type(8))) short short8;
typedef __attribute__((ext_vector_type(4))) float f32x4;

__device__ __forceinline__ float bf2f(u16 u) {
    union { u32 i; float f; } x; x.i = ((u32)u) << 16; return x.f;
}
__device__ __forceinline__ u16 f2bf(float f) {
    union { u32 i; float f; } x; x.f = f;
    u32 u = x.i;
    return (u16)((u + 0x7fffu + ((u >> 16) & 1u)) >> 16);
}
__device__ __forceinline__ float bflo(u32 w) {
    union { u32 i; float f; } x; x.i = w << 16; return x.f;
}
__device__ __forceinline__ float bfhi(u32 w) {
    union { u32 i; float f; } x; x.i = w & 0xffff0000u; return x.f;
}
__device__ __forceinline__ u32 pk2(float lo, float hi) {
    return (u32)f2bf(lo) | ((u32)f2bf(hi) << 16);
}

// ============ CSR build ============
__global__ void k_count(const int* __restrict__ edst, int* __restrict__ deg) {
    int e = blockIdx.x * 256 + threadIdx.x;
    if (e < NED) atomicAdd(&deg[edst[e]], 1);
}

__global__ void k_bsum(const int* __restrict__ deg, int* __restrict__ bsums) {
    int i = blockIdx.x * 256 + threadIdx.x;
    int v = (i < NND) ? deg[i] : 0;
    #pragma unroll
    for (int m = 1; m < 64; m <<= 1) v += __shfl_xor(v, m, 64);
    __shared__ int ls[4];
    if ((threadIdx.x & 63) == 0) ls[threadIdx.x >> 6] = v;
    __syncthreads();
    if (threadIdx.x == 0) bsums[blockIdx.x] = ls[0] + ls[1] + ls[2] + ls[3];
}

__global__ void k_scan(int* __restrict__ bsums) {
    __shared__ int a[256];
    int t = threadIdx.x;
    int v = (t < NCH) ? bsums[t] : 0;
    a[t] = v;
    __syncthreads();
    for (int off = 1; off < 256; off <<= 1) {
        int add = (t >= off) ? a[t - off] : 0;
        __syncthreads();
        a[t] += add;
        __syncthreads();
    }
    if (t < NCH) bsums[t] = a[t] - v;
}

__global__ void k_offsets(const int* __restrict__ deg, const int* __restrict__ bsums,
                          int* __restrict__ offs, int* __restrict__ cursor) {
    __shared__ int a[256];
    int t = threadIdx.x;
    int i = blockIdx.x * 256 + t;
    int v = (i < NND) ? deg[i] : 0;
    a[t] = v;
    __syncthreads();
    for (int off = 1; off < 256; off <<= 1) {
        int add = (t >= off) ? a[t - off] : 0;
        __syncthreads();
        a[t] += add;
        __syncthreads();
    }
    int excl = bsums[blockIdx.x] + a[t] - v;
    if (i < NND) {
        offs[i] = excl;
        cursor[i] = excl;
        if (i == NND - 1) offs[NND] = excl + v;
    }
}

__global__ void k_fill(const int* __restrict__ esrc, const int* __restrict__ edst,
                       int* __restrict__ cursor, int* __restrict__ csr) {
    int e = blockIdx.x * 256 + threadIdx.x;
    if (e < NED) {
        int pos = atomicAdd(&cursor[edst[e]], 1);
        csr[pos] = esrc[e];
    }
}

// ============ weight prep ============
__global__ void k_wt(const float* __restrict__ Wq, const float* __restrict__ Wk,
                     const float* __restrict__ Wv, const float* __restrict__ Ws,
                     const float* __restrict__ Wp,
                     const float* __restrict__ bq, const float* __restrict__ bk,
                     const float* __restrict__ bv, const float* __restrict__ bs,
                     u16* __restrict__ wb, float* __restrict__ bias_c,
                     float* __restrict__ wpt) {
    int idx = blockIdx.x * 256 + threadIdx.x;
    if (idx < 65536) {
        int j = idx & 7;
        int lane = (idx >> 3) & 63;
        int q = (idx >> 9) & 1;
        int dt = idx >> 10;
        int dim = dt * 16 + (lane & 15);
        int k = q * 32 + ((lane >> 4) & 3) * 8 + j;
        int mat = dim >> 8, r = dim & 255;
        const float* W = (mat == 0) ? Wq : (mat == 1) ? Wk : (mat == 2) ? Wv : Ws;
        float v = W[r * 64 + k] * ((mat == 0) ? 0.125f : 1.0f);
        wb[idx] = f2bf(v);
    } else if (idx < 65536 + 1024) {
        int dim = idx - 65536;
        int mat = dim >> 8, r = dim & 255;
        const float* B = (mat == 0) ? bq : (mat == 1) ? bk : (mat == 2) ? bv : bs;
        bias_c[dim] = B[r] * ((mat == 0) ? 0.125f : 1.0f);
    } else if (idx < 65536 + 1024 + 16384) {
        int w = idx - 66560;
        int o = w >> 8, c = w & 255;
        wpt[c * 64 + o] = Wp[w];
    }
}

// ============ fused q/k/v/skip projections via MFMA, LDS-staged stores ============
// 64 nodes/block in 4 phases of 16; wave w computes dims [w*256, w*256+256).
// qkvs[node][1024] bf16: [q(0-255) | k(256-511) | v(512-767) | xr(768-1023)]
#define PPAD 1040
__global__ __launch_bounds__(256) void k_proj(
    const float* __restrict__ x, const u16* __restrict__ wb,
    const float* __restrict__ bias_c, u16* __restrict__ qkvs)
{
    __shared__ u16 hb[16 * PPAD];   // 33,280 B
    const int t = threadIdx.x;
    const int wave = t >> 6, lane = t & 63;
    const int nbase = blockIdx.x * 64;
    const int lr = lane & 15, quad = lane >> 4;

    for (int nt = 0; nt < 4; ++nt) {
        const int node0 = nbase + nt * 16;          // block-uniform
        if (node0 >= NND) break;
        // B-operand x fragment for this 16-node tile: lane holds x[n=lr][k=quad*8+j]
        int node = node0 + lr;
        if (node > NND - 1) node = NND - 1;
        short8 xf0, xf1;
        {
            const float* xp = x + (size_t)node * 64 + quad * 8;
            float4 a = *reinterpret_cast<const float4*>(xp);
            float4 b = *reinterpret_cast<const float4*>(xp + 4);
            float4 c = *reinterpret_cast<const float4*>(xp + 32);
            float4 d = *reinterpret_cast<const float4*>(xp + 36);
            xf0[0] = (short)f2bf(a.x); xf0[1] = (short)f2bf(a.y);
            xf0[2] = (short)f2bf(a.z); xf0[3] = (short)f2bf(a.w);
            xf0[4] = (short)f2bf(b.x); xf0[5] = (short)f2bf(b.y);
            xf0[6] = (short)f2bf(b.z); xf0[7] = (short)f2bf(b.w);
            xf1[0] = (short)f2bf(c.x); xf1[1] = (short)f2bf(c.y);
            xf1[2] = (short)f2bf(c.z); xf1[3] = (short)f2bf(c.w);
            xf1[4] = (short)f2bf(d.x); xf1[5] = (short)f2bf(d.y);
            xf1[6] = (short)f2bf(d.z); xf1[7] = (short)f2bf(d.w);
        }
        #pragma unroll 4
        for (int dtl = 0; dtl < 16; ++dtl) {
            int dt = wave * 16 + dtl;
            const u16* wp = wb + (size_t)(dt * 2) * 512 + lane * 8;
            short8 a0 = *reinterpret_cast<const short8*>(wp);
            short8 a1 = *reinterpret_cast<const short8*>(wp + 512);
            f32x4 bias = *reinterpret_cast<const f32x4*>(bias_c + dt * 16 + quad * 4);
            f32x4 acc = {0.f, 0.f, 0.f, 0.f};
            acc = __builtin_amdgcn_mfma_f32_16x16x32_bf16(a0, xf0, acc, 0, 0, 0);
            acc = __builtin_amdgcn_mfma_f32_16x16x32_bf16(a1, xf1, acc, 0, 0, 0);
            // C layout: col(lane&15)=node-in-tile, row(quad*4+reg)=dim-in-tile
            uint2 st;
            st.x = pk2(acc[0] + bias[0], acc[1] + bias[1]);
            st.y = pk2(acc[2] + bias[2], acc[3] + bias[3]);
            *reinterpret_cast<uint2*>(&hb[lr * PPAD + dt * 16 + quad * 4]) = st;
        }
        __syncthreads();
        // coalesced store: 16 nodes x 2KB = 32KB, 8 iters x 256 thr x 16B
        #pragma unroll
        for (int it = 0; it < 8; ++it) {
            int idx = it * 256 + t;
            int nip = idx >> 7, col = idx & 127;
            int gnode = node0 + nip;
            if (gnode < NND) {
                *reinterpret_cast<uint4*>(qkvs + (size_t)gnode * 1024 + col * 8) =
                    *reinterpret_cast<const uint4*>(&hb[nip * PPAD + col * 8]);
            }
        }
        __syncthreads();
    }
}

// ============ per-node attention, no-max softmax (logits bounded ~|1|) ============
// lane = half(2) x 32 lanes x 8 channels; head = ((lane&31)>>3)
__global__ __launch_bounds__(256) void k_attn(
    const int* __restrict__ offs, const int* __restrict__ csr,
    u16* __restrict__ qkvs)
{
    const int wave = threadIdx.x >> 6;
    const int lane = threadIdx.x & 63;
    const int node = blockIdx.x * 4 + wave;
    if (node >= NND) return;
    const int l32 = lane & 31;
    const int half = lane >> 5;
    const int ch0 = l32 * 8;
    u16* nrow = qkvs + (size_t)node * 1024;

    uint4 qv = *reinterpret_cast<const uint4*>(nrow + ch0);
    float q0 = bflo(qv.x), q1 = bfhi(qv.x), q2 = bflo(qv.y), q3 = bfhi(qv.y);
    float q4 = bflo(qv.z), q5 = bfhi(qv.z), q6 = bflo(qv.w), q7 = bfhi(qv.w);

    int r0 = __builtin_amdgcn_readfirstlane(offs[node]);
    int r1 = __builtin_amdgcn_readfirstlane(offs[node + 1]);

    float s = 0.f;
    float a0 = 0.f, a1 = 0.f, a2 = 0.f, a3 = 0.f;
    float a4 = 0.f, a5 = 0.f, a6 = 0.f, a7 = 0.f;

    int i = r0;
    for (; i + 8 <= r1; i += 8) {
        // 8 uniform csr loads (stay scalar), halves split 4/4
        int c0 = csr[i + 0], c1 = csr[i + 1], c2 = csr[i + 2], c3 = csr[i + 3];
        int c4 = csr[i + 4], c5 = csr[i + 5], c6 = csr[i + 6], c7 = csr[i + 7];
        int e0 = half ? c4 : c0;
        int e1 = half ? c5 : c1;
        int e2 = half ? c6 : c2;
        int e3 = half ? c7 : c3;
        const u16* p0 = qkvs + (size_t)e0 * 1024;
        const u16* p1 = qkvs + (size_t)e1 * 1024;
        const u16* p2 = qkvs + (size_t)e2 * 1024;
        const u16* p3 = qkvs + (size_t)e3 * 1024;
        uint4 k0 = *reinterpret_cast<const uint4*>(p0 + 256 + ch0);
        uint4 v0 = *reinterpret_cast<const uint4*>(p0 + 512 + ch0);
        uint4 k1 = *reinterpret_cast<const uint4*>(p1 + 256 + ch0);
        uint4 v1 = *reinterpret_cast<const uint4*>(p1 + 512 + ch0);
        uint4 k2 = *reinterpret_cast<const uint4*>(p2 + 256 + ch0);
        uint4 v2 = *reinterpret_cast<const uint4*>(p2 + 512 + ch0);
        uint4 k3 = *reinterpret_cast<const uint4*>(p3 + 256 + ch0);
        uint4 v3 = *reinterpret_cast<const uint4*>(p3 + 512 + ch0);

        float pa = q0*bflo(k0.x) + q1*bfhi(k0.x) + q2*bflo(k0.y) + q3*bfhi(k0.y)
                 + q4*bflo(k0.z) + q5*bfhi(k0.z) + q6*bflo(k0.w) + q7*bfhi(k0.w);
        float pb = q0*bflo(k1.x) + q1*bfhi(k1.x) + q2*bflo(k1.y) + q3*bfhi(k1.y)
                 + q4*bflo(k1.z) + q5*bfhi(k1.z) + q6*bflo(k1.w) + q7*bfhi(k1.w);
        float pc = q0*bflo(k2.x) + q1*bfhi(k2.x) + q2*bflo(k2.y) + q3*bfhi(k2.y)
                 + q4*bflo(k2.z) + q5*bfhi(k2.z) + q6*bflo(k2.w) + q7*bfhi(k2.w);
        float pd = q0*bflo(k3.x) + q1*bfhi(k3.x) + q2*bflo(k3.y) + q3*bfhi(k3.y)
                 + q4*bflo(k3.z) + q5*bfhi(k3.z) + q6*bflo(k3.w) + q7*bfhi(k3.w);
        pa += __shfl_xor(pa, 1); pa += __shfl_xor(pa, 2); pa += __shfl_xor(pa, 4);
        pb += __shfl_xor(pb, 1); pb += __shfl_xor(pb, 2); pb += __shfl_xor(pb, 4);
        pc += __shfl_xor(pc, 1); pc += __shfl_xor(pc, 2); pc += __shfl_xor(pc, 4);
        pd += __shfl_xor(pd, 1); pd += __shfl_xor(pd, 2); pd += __shfl_xor(pd, 4);
        float ea = __expf(pa), eb = __expf(pb), ec = __expf(pc), ed = __expf(pd);
        s += (ea + eb) + (ec + ed);
        a0 = fmaf(ea, bflo(v0.x), fmaf(eb, bflo(v1.x), fmaf(ec, bflo(v2.x), fmaf(ed, bflo(v3.x), a0))));
        a1 = fmaf(ea, bfhi(v0.x), fmaf(eb, bfhi(v1.x), fmaf(ec, bfhi(v2.x), fmaf(ed, bfhi(v3.x), a1))));
        a2 = fmaf(ea, bflo(v0.y), fmaf(eb, bflo(v1.y), fmaf(ec, bflo(v2.y), fmaf(ed, bflo(v3.y), a2))));
        a3 = fmaf(ea, bfhi(v0.y), fmaf(eb, bfhi(v1.y), fmaf(ec, bfhi(v2.y), fmaf(ed, bfhi(v3.y), a3))));
        a4 = fmaf(ea, bflo(v0.z), fmaf(eb, bflo(v1.z), fmaf(ec, bflo(v2.z), fmaf(ed, bflo(v3.z), a4))));
        a5 = fmaf(ea, bfhi(v0.z), fmaf(eb, bfhi(v1.z), fmaf(ec, bfhi(v2.z), fmaf(ed, bfhi(v3.z), a5))));
        a6 = fmaf(ea, bflo(v0.w), fmaf(eb, bflo(v1.w), fmaf(ec, bflo(v2.w), fmaf(ed, bflo(v3.w), a6))));
        a7 = fmaf(ea, bfhi(v0.w), fmaf(eb, bfhi(v1.w), fmaf(ec, bfhi(v2.w), fmaf(ed, bfhi(v3.w), a7))));
    }
    for (; i < r1; i += 2) {
        int ii = i + half;
        bool valid = ii < r1;
        if (ii > r1 - 1) ii = r1 - 1;
        int e0 = csr[ii];
        const u16* p0 = qkvs + (size_t)e0 * 1024;
        uint4 k0 = *reinterpret_cast<const uint4*>(p0 + 256 + ch0);
        uint4 v0 = *reinterpret_cast<const uint4*>(p0 + 512 + ch0);
        float pa = q0*bflo(k0.x) + q1*bfhi(k0.x) + q2*bflo(k0.y) + q3*bfhi(k0.y)
                 + q4*bflo(k0.z) + q5*bfhi(k0.z) + q6*bflo(k0.w) + q7*bfhi(k0.w);
        pa += __shfl_xor(pa, 1); pa += __shfl_xor(pa, 2); pa += __shfl_xor(pa, 4);
        float ea = valid ? __expf(pa) : 0.f;
        s += ea;
        a0 = fmaf(ea, bflo(v0.x), a0);
        a1 = fmaf(ea, bfhi(v0.x), a1);
        a2 = fmaf(ea, bflo(v0.y), a2);
        a3 = fmaf(ea, bfhi(v0.y), a3);
        a4 = fmaf(ea, bflo(v0.z), a4);
        a5 = fmaf(ea, bfhi(v0.z), a5);
        a6 = fmaf(ea, bflo(v0.w), a6);
        a7 = fmaf(ea, bfhi(v0.w), a7);
    }
    // combine halves, normalize, store into (dead) q-section as `out`
    s  += __shfl_xor(s, 32);
    a0 += __shfl_xor(a0, 32); a1 += __shfl_xor(a1, 32);
    a2 += __shfl_xor(a2, 32); a3 += __shfl_xor(a3, 32);
    a4 += __shfl_xor(a4, 32); a5 += __shfl_xor(a5, 32);
    a6 += __shfl_xor(a6, 32); a7 += __shfl_xor(a7, 32);
    float inv = 1.0f / (s + 1e-16f);
    if (half == 0) {
        uint4 st;
        st.x = pk2(a0 * inv, a1 * inv);
        st.y = pk2(a2 * inv, a3 * inv);
        st.z = pk2(a4 * inv, a5 * inv);
        st.w = pk2(a6 * inv, a7 * inv);
        *reinterpret_cast<uint4*>(nrow + ch0) = st;
    }
}

// ============ epilogue: beta gate + LayerNorm + proj + residual ReLU ============
#define PS 260   // LDS row stride in u16
__global__ __launch_bounds__(256) void k_epi(
    const u16* __restrict__ qkvs, const float* __restrict__ x,
    const float* __restrict__ Wbeta, const float* __restrict__ ln_g,
    const float* __restrict__ ln_b, const float* __restrict__ wpt,
    const float* __restrict__ bproj, float* __restrict__ y)
{
    __shared__ u16 hn[64 * PS];
    const int t = threadIdx.x;
    const int wave = t >> 6, lane = t & 63;
    const float4* wb4 = reinterpret_cast<const float4*>(Wbeta);
    const float4 wbo = wb4[lane], wbx = wb4[64 + lane], wbd = wb4[128 + lane];
    const float4 g4 = reinterpret_cast<const float4*>(ln_g)[lane];
    const float4 b4 = reinterpret_cast<const float4*>(ln_b)[lane];
    const int og = t & 15, ng = t >> 4;
    const float4 bp4 = reinterpret_cast<const float4*>(bproj)[og];
    const float4* wpt4 = reinterpret_cast<const float4*>(wpt);

    const int base = blockIdx.x * 64;
    for (int it = 0; it < 16; ++it) {
        int lid = wave * 16 + it;
        int node = base + lid;
        if (node < NND) {
            const u16* nrow = qkvs + (size_t)node * 1024;
            ushort4 ou = *reinterpret_cast<const ushort4*>(nrow + lane * 4);        // out
            ushort4 xu = *reinterpret_cast<const ushort4*>(nrow + 768 + lane * 4);  // x_r
            float o0 = bf2f(ou.x), o1 = bf2f(ou.y), o2 = bf2f(ou.z), o3 = bf2f(ou.w);
            float r0 = bf2f(xu.x), r1 = bf2f(xu.y), r2 = bf2f(xu.z), r3 = bf2f(xu.w);
            float part = wbo.x*o0 + wbo.y*o1 + wbo.z*o2 + wbo.w*o3
                       + wbx.x*r0 + wbx.y*r1 + wbx.z*r2 + wbx.w*r3
                       + wbd.x*(o0-r0) + wbd.y*(o1-r1) + wbd.z*(o2-r2) + wbd.w*(o3-r3);
            #pragma unroll
            for (int mm = 1; mm < 64; mm <<= 1) part += __shfl_xor(part, mm, 64);
            float beta = 1.0f / (1.0f + __expf(-part));
            float h0 = beta * r0 + (1.f - beta) * o0;
            float h1 = beta * r1 + (1.f - beta) * o1;
            float h2 = beta * r2 + (1.f - beta) * o2;
            float h3 = beta * r3 + (1.f - beta) * o3;
            float sh = h0 + h1 + h2 + h3;
            float sq = h0*h0 + h1*h1 + h2*h2 + h3*h3;
            #pragma unroll
            for (int mm = 1; mm < 64; mm <<= 1) {
                sh += __shfl_xor(sh, mm, 64);
                sq += __shfl_xor(sq, mm, 64);
            }
            float mu = sh * (1.0f / 256.0f);
            float var = sq * (1.0f / 256.0f) - mu * mu;
            float ri = rsqrtf(var + 1e-5f);
            ushort4 hv;
            hv.x = f2bf((h0 - mu) * ri * g4.x + b4.x);
            hv.y = f2bf((h1 - mu) * ri * g4.y + b4.y);
            hv.z = f2bf((h2 - mu) * ri * g4.z + b4.z);
            hv.w = f2bf((h3 - mu) * ri * g4.w + b4.w);
            *reinterpret_cast<ushort4*>(&hn[lid * PS + lane * 4]) = hv;
        }
    }
    __syncthreads();
    float acc[4][4];
    #pragma unroll
    for (int a = 0; a < 4; ++a)
        #pragma unroll
        for (int b = 0; b < 4; ++b) acc[a][b] = 0.f;
    for (int c4 = 0; c4 < 64; ++c4) {
        int c = c4 * 4;
        float4 w0 = wpt4[(c + 0) * 16 + og];
        float4 w1 = wpt4[(c + 1) * 16 + og];
        float4 w2 = wpt4[(c + 2) * 16 + og];
        float4 w3 = wpt4[(c + 3) * 16 + og];
        #pragma unroll
        for (int nn = 0; nn < 4; ++nn) {
            ushort4 hu = *reinterpret_cast<const ushort4*>(&hn[(ng * 4 + nn) * PS + c]);
            float h0 = bf2f(hu.x), h1 = bf2f(hu.y), h2 = bf2f(hu.z), h3 = bf2f(hu.w);
            acc[nn][0] = fmaf(h0, w0.x, acc[nn][0]);
            acc[nn][1] = fmaf(h0, w0.y, acc[nn][1]);
            acc[nn][2] = fmaf(h0, w0.z, acc[nn][2]);
            acc[nn][3] = fmaf(h0, w0.w, acc[nn][3]);
            acc[nn][0] = fmaf(h1, w1.x, acc[nn][0]);
            acc[nn][1] = fmaf(h1, w1.y, acc[nn][1]);
            acc[nn][2] = fmaf(h1, w1.z, acc[nn][2]);
            acc[nn][3] = fmaf(h1, w1.w, acc[nn][3]);
            acc[nn][0] = fmaf(h2, w2.x, acc[nn][0]);
            acc[nn][1] = fmaf(h2, w2.y, acc[nn][1]);
            acc[nn][2] = fmaf(h2, w2.z, acc[nn][2]);
            acc[nn][3] = fmaf(h2, w2.w, acc[nn][3]);
            acc[nn][0] = fmaf(h3, w3.x, acc[nn][0]);
            acc[nn][1] = fmaf(h3, w3.y, acc[nn][1]);
            acc[nn][2] = fmaf(h3, w3.z, acc[nn][2]);
            acc[nn][3] = fmaf(h3, w3.w, acc[nn][3]);
        }
    }
    #pragma unroll
    for (int nn = 0; nn < 4; ++nn) {
        int node = base + ng * 4 + nn;
        if (node < NND) {
            float4 xv = reinterpret_cast<const float4*>(x)[node * 16 + og];
            float4 r;
            r.x = fmaxf(acc[nn][0] + bp4.x + xv.x, 0.f);
            r.y = fmaxf(acc[nn][1] + bp4.y + xv.y, 0.f);
            r.z = fmaxf(acc[nn][2] + bp4.z + xv.z, 0.f);
            r.w = fmaxf(acc[nn][3] + bp4.w + xv.w, 0.f);
            reinterpret_cast<float4*>(y)[node * 16 + og] = r;
        }
    }
}

extern "C" void kernel_launch(void* const* d_in, const int* in_sizes, int n_in,
                              void* d_out, int out_size, void* d_ws, size_t ws_size,
                              hipStream_t stream) {
    const float* x     = (const float*)d_in[0];
    const int*   eidx  = (const int*)d_in[1];
    const float* Wq    = (const float*)d_in[2];
    const float* bq    = (const float*)d_in[3];
    const float* Wk    = (const float*)d_in[4];
    const float* bk    = (const float*)d_in[5];
    const float* Wv    = (const float*)d_in[6];
    const float* bv    = (const float*)d_in[7];
    const float* Wsk   = (const float*)d_in[8];
    const float* bsk   = (const float*)d_in[9];
    const float* Wbeta = (const float*)d_in[10];
    const float* lng   = (const float*)d_in[11];
    const float* lnb   = (const float*)d_in[12];
    const float* Wp    = (const float*)d_in[13];
    const float* bp    = (const float*)d_in[14];
    float* y = (float*)d_out;

    char* ws = (char*)d_ws;
    size_t off = 0;
    auto alloc = [&](size_t b) { size_t o = off; off += (b + 255) & ~(size_t)255; return o; };
    u16* qkvs = (u16*)(ws + alloc((size_t)NND * 1024 * 2));
    int* deg    = (int*)(ws + alloc((size_t)NND * 4));
    int* offs   = (int*)(ws + alloc((size_t)(NND + 1) * 4));
    int* cursor = (int*)(ws + alloc((size_t)NND * 4));
    int* csr    = (int*)(ws + alloc((size_t)NED * 4));
    int* bsums  = (int*)(ws + alloc((size_t)NCH * 4));
    u16* wb     = (u16*)(ws + alloc((size_t)65536 * 2));
    float* bias_c = (float*)(ws + alloc((size_t)1024 * 4));
    float* wpt  = (float*)(ws + alloc((size_t)16384 * 4));

    hipMemsetAsync(deg, 0, (size_t)NND * 4, stream);
    k_count  <<<(NED + 255) / 256, 256, 0, stream>>>(eidx + NED, deg);
    k_bsum   <<<NCH, 256, 0, stream>>>(deg, bsums);
    k_scan   <<<1, 256, 0, stream>>>(bsums);
    k_offsets<<<NCH, 256, 0, stream>>>(deg, bsums, offs, cursor);
    k_fill   <<<(NED + 255) / 256, 256, 0, stream>>>(eidx, eidx + NED, cursor, csr);
    k_wt     <<<(66560 + 16384 + 255) / 256, 256, 0, stream>>>(
                 Wq, Wk, Wv, Wsk, Wp, bq, bk, bv, bsk, wb, bias_c, wpt);
    k_proj   <<<(NND + 63) / 64, 256, 0, stream>>>(x, wb, bias_c, qkvs);
    k_attn   <<<(NND + 3) / 4, 256, 0, stream>>>(offs, csr, qkvs);
    k_epi    <<<(NND + 63) / 64, 256, 0, stream>>>(qkvs, x, Wbeta, lng, lnb, wpt, bp, y);
}